// Round 8
// baseline (12.831 us; speedup 1.0000x reference)
//
#include <hip/hip_runtime.h>
#include <hip/hip_bf16.h>
#include <math.h>

#define NFEAT 10
#define DICT 10000

typedef __attribute__((ext_vector_type(8))) short bf16x8;
typedef __attribute__((ext_vector_type(4))) float f32x4;
typedef __attribute__((ext_vector_type(4))) unsigned u32x4;

__device__ inline unsigned short f2bf(float f) {
    __hip_bfloat16 h = __float2bfloat16(f);   // RNE; pairs fuse to v_cvt_pk
    unsigned short s;
    __builtin_memcpy(&s, &h, sizeof(s));
    return s;
}
__device__ inline unsigned cvt2(float lo, float hi) {
    return (unsigned)f2bf(lo) | ((unsigned)f2bf(hi) << 16);   // 2x bf16 packed
}

// block = 256 thr = 4 waves = ONE 16-example tile.
//   wid 0: plain path, k=0..15, + exact-f32 linear term
//   wid 1: plain path, k=16..31
//   wid 2: squared path, k=0..15
//   wid 3: squared path, k=16..31
// Every wave gathers its lanes' x slices directly (duplicates are same-CU
// L1/L2 hits and add memory-level parallelism); one barrier; 320 B LDS.
__global__ __launch_bounds__(256, 4) void fm_fused(
    const int* __restrict__ inputs,
    const float* __restrict__ user_table,
    const float* __restrict__ item_table,
    const float* __restrict__ feat_tables,
    const float* __restrict__ wvec,
    const float* __restrict__ bb,
    const float* __restrict__ k_mat,
    float* __restrict__ out)
{
    __shared__ float part[5][16];   // [0..1]: s^2 halves, [2..3]: t halves, [4]: lin

    const int tid   = threadIdx.x;
    const int lane  = tid & 63;
    const int wid   = tid >> 6;          // 0..3
    const int gtile = blockIdx.x;
    const int col   = lane & 15;         // example row (A) / k col (C)
    const int kg    = lane >> 4;         // 8-dim chunk group
    const int e     = gtile * 16 + col;
    const int fsel  = kg >> 1;           // even/odd feature
    const int hoff  = (kg & 1) * 8;      // half of the 16-float embedding
    const int kh    = (wid & 1) * 16;    // this wave's k-half
    const bool sq   = (wid >= 2);        // squared path?

    // ---- index loads (5 per lane) ----
    int idx[5];
    #pragma unroll
    for (int c = 0; c < 5; ++c)
        idx[c] = inputs[e * NFEAT + 2 * c + fsel];

    // ---- gather x slices in f32 (10 independent dwordx4, issued early) ----
    float4 u0[5], u1[5];
    #pragma unroll
    for (int c = 0; c < 5; ++c) {
        const float* tbl = (c == 0)
            ? (fsel ? item_table : user_table)
            : (feat_tables + (size_t)(2 * c + fsel - 2) * (DICT * 16));
        const float* src = tbl + (size_t)idx[c] * 16 + hoff;
        u0[c] = *(const float4*)src;
        u1[c] = *(const float4*)(src + 4);
    }

    // ---- B fragment for this wave's k-half (k_mat 20 KB, L1/L2-resident) ----
    bf16x8 bf[5];
    #pragma unroll
    for (int c = 0; c < 5; ++c) {
        const int dbase = c * 32 + kg * 8;
        float f[8];
        #pragma unroll
        for (int j = 0; j < 8; ++j)
            f[j] = k_mat[(dbase + j) * 32 + kh + col];
        if (sq) {
            #pragma unroll
            for (int j = 0; j < 8; ++j) f[j] *= f[j];
        }
        u32x4 p;
        #pragma unroll
        for (int j = 0; j < 4; ++j)
            p[j] = cvt2(f[2*j], f[2*j+1]);
        bf[c] = __builtin_bit_cast(bf16x8, p);
    }

    // ---- A fragments + 5 MFMAs ----
    f32x4 acc = {0, 0, 0, 0};
    #pragma unroll
    for (int c = 0; c < 5; ++c) {
        float4 v0 = u0[c], v1 = u1[c];
        if (sq) {
            v0.x *= v0.x; v0.y *= v0.y; v0.z *= v0.z; v0.w *= v0.w;
            v1.x *= v1.x; v1.y *= v1.y; v1.z *= v1.z; v1.w *= v1.w;
        }
        u32x4 p;
        p[0] = cvt2(v0.x, v0.y); p[1] = cvt2(v0.z, v0.w);
        p[2] = cvt2(v1.x, v1.y); p[3] = cvt2(v1.z, v1.w);
        bf16x8 a = __builtin_bit_cast(bf16x8, p);
        acc = __builtin_amdgcn_mfma_f32_16x16x32_bf16(a, bf[c], acc, 0, 0, 0);
    }

    // ---- wave 0: exact-f32 linear term ----
    if (wid == 0) {
        float lin = 0.f;
        #pragma unroll
        for (int c = 0; c < 5; ++c) {
            const int dbase = c * 32 + kg * 8;
            float4 w0 = *(const float4*)&wvec[dbase];
            float4 w1 = *(const float4*)&wvec[dbase + 4];
            lin = fmaf(u0[c].x, w0.x, lin); lin = fmaf(u0[c].y, w0.y, lin);
            lin = fmaf(u0[c].z, w0.z, lin); lin = fmaf(u0[c].w, w0.w, lin);
            lin = fmaf(u1[c].x, w1.x, lin); lin = fmaf(u1[c].y, w1.y, lin);
            lin = fmaf(u1[c].z, w1.z, lin); lin = fmaf(u1[c].w, w1.w, lin);
        }
        lin += __shfl_xor(lin, 16, 64);
        lin += __shfl_xor(lin, 32, 64);        // full lin for example=col
        if (lane < 16) part[4][lane] = lin;    // kg==0 lanes
    }

    // ---- per-wave reduction over its 16 k-cols; C row = kg*4 + r ----
    #pragma unroll
    for (int r = 0; r < 4; ++r) {
        float v = sq ? acc[r] : acc[r] * acc[r];
        #pragma unroll
        for (int m = 1; m <= 8; m <<= 1)
            v += __shfl_xor(v, m, 64);         // sum over the 16 cols
        if (col == 0) part[wid][kg * 4 + r] = v;
    }
    __syncthreads();

    // ---- combine + sigmoid (16 threads, coalesced 64B store) ----
    if (tid < 16) {
        float s2 = part[0][tid] + part[1][tid];
        float t  = part[2][tid] + part[3][tid];
        float z  = part[4][tid] + bb[0] + 0.5f * (s2 - t);
        out[gtile * 16 + tid] = 1.0f / (1.0f + __expf(-z));
    }
}

extern "C" void kernel_launch(void* const* d_in, const int* in_sizes, int n_in,
                              void* d_out, int out_size, void* d_ws, size_t ws_size,
                              hipStream_t stream) {
    const int*   inputs      = (const int*)  d_in[0];
    const float* user_table  = (const float*)d_in[1];
    const float* item_table  = (const float*)d_in[2];
    const float* feat_tables = (const float*)d_in[3];
    const float* w           = (const float*)d_in[4];
    const float* b           = (const float*)d_in[5];
    const float* k_mat       = (const float*)d_in[6];
    float* out = (float*)d_out;

    int nblocks = out_size / 16;    // 16384 / 16 = 1024 blocks, 4 waves each
    fm_fused<<<nblocks, 256, 0, stream>>>(inputs, user_table, item_table,
                                          feat_tables, w, b, k_mat, out);
}

// Round 9
// 11.669 us; speedup vs baseline: 1.0996x; 1.0996x over previous
//
#include <hip/hip_runtime.h>
#include <hip/hip_bf16.h>
#include <math.h>

#define NFEAT 10
#define DICT 10000
#define KP32 84            // dword pitch of K^T LDS image (336 B, 16B-aligned)

typedef __attribute__((ext_vector_type(8))) short bf16x8;
typedef __attribute__((ext_vector_type(4))) float f32x4;
typedef __attribute__((ext_vector_type(4))) unsigned u32x4;

__device__ inline unsigned short f2bf(float f) {
    __hip_bfloat16 h = __float2bfloat16(f);   // RNE; pairs fuse to v_cvt_pk
    unsigned short s;
    __builtin_memcpy(&s, &h, sizeof(s));
    return s;
}
__device__ inline unsigned cvt2(float lo, float hi) {
    return (unsigned)f2bf(lo) | ((unsigned)f2bf(hi) << 16);   // 2x bf16 packed
}

// block = 256 thr = 4 waves; each wave owns one 16-example tile.
// Per wave: s_k (k=0..31) via 10 bf16 MFMAs; lin = x.w and t = x^2.kk2 exact
// in f32 VALU; one barrier; K^T staged once per block as bf16 in LDS.
__global__ __launch_bounds__(256) void fm_fused(
    const int* __restrict__ inputs,
    const float* __restrict__ user_table,
    const float* __restrict__ item_table,
    const float* __restrict__ feat_tables,
    const float* __restrict__ wvec,
    const float* __restrict__ bb,
    const float* __restrict__ k_mat,
    float* __restrict__ out)
{
    __shared__ unsigned ldsK32[32 * KP32];   // K^T bf16: elem16[k*168 + d] = bf16(K[d][k])
    __shared__ float    kk2s[160];           // kk2[d] = sum_k K[d][k]^2

    const int tid  = threadIdx.x;
    const int lane = tid & 63;
    const int wid  = tid >> 6;
    const int tile = blockIdx.x * 4 + wid;
    const int col  = lane & 15;          // example row (A) / k col (C)
    const int kg   = lane >> 4;          // 8-dim chunk group
    const int e    = tile * 16 + col;
    const int fsel = kg >> 1;            // even/odd feature
    const int hoff = (kg & 1) * 8;       // half of the 16-float embedding

    // ---- 1. issue idx + gather loads FIRST (latency hides under preamble) --
    int idx[5];
    #pragma unroll
    for (int c = 0; c < 5; ++c)
        idx[c] = inputs[e * NFEAT + 2 * c + fsel];

    float4 u0[5], u1[5];
    #pragma unroll
    for (int c = 0; c < 5; ++c) {
        const float* tbl = (c == 0)
            ? (fsel ? item_table : user_table)
            : (feat_tables + (size_t)(2 * c + fsel - 2) * (DICT * 16));
        const float* src = tbl + (size_t)idx[c] * 16 + hoff;
        u0[c] = *(const float4*)src;
        u1[c] = *(const float4*)(src + 4);
    }

    // ---- 2. preamble: stage K^T (bf16, packed u32 writes) + kk2 ----
    #pragma unroll
    for (int u = 0; u < 10; ++u) {
        int i  = tid + 256 * u;          // i = k*80 + d2, 2560 total
        int k  = i / 80;
        int d2 = i - k * 80;
        float flo = k_mat[(2 * d2)     * 32 + k];
        float fhi = k_mat[(2 * d2 + 1) * 32 + k];
        ldsK32[k * KP32 + d2] = cvt2(flo, fhi);
    }
    if (tid < 160) {
        const float4* row = (const float4*)(k_mat + tid * 32);
        float acc = 0.f;
        #pragma unroll
        for (int u = 0; u < 8; ++u) {
            float4 v = row[u];
            acc = fmaf(v.x, v.x, acc); acc = fmaf(v.y, v.y, acc);
            acc = fmaf(v.z, v.z, acc); acc = fmaf(v.w, v.w, acc);
        }
        kk2s[tid] = acc;
    }
    __syncthreads();

    const unsigned short* ldsK16 = (const unsigned short*)ldsK32;

    // ---- 3. B fragments: 10 ds_read_b128 ----
    bf16x8 b0[5], b1[5];
    #pragma unroll
    for (int c = 0; c < 5; ++c) {
        const int dbase = c * 32 + kg * 8;
        b0[c] = *(const bf16x8*)&ldsK16[(col)      * (2 * KP32) + dbase];
        b1[c] = *(const bf16x8*)&ldsK16[(col + 16) * (2 * KP32) + dbase];
    }

    // ---- 4. A fragments + 10 MFMAs; lin/t in exact f32 alongside ----
    f32x4 acc0 = {0,0,0,0};   // s, k = 0..15
    f32x4 acc1 = {0,0,0,0};   // s, k = 16..31
    float lin = 0.f, tq = 0.f;
    #pragma unroll
    for (int c = 0; c < 5; ++c) {
        const int dbase = c * 32 + kg * 8;
        u32x4 p;
        p[0] = cvt2(u0[c].x, u0[c].y); p[1] = cvt2(u0[c].z, u0[c].w);
        p[2] = cvt2(u1[c].x, u1[c].y); p[3] = cvt2(u1[c].z, u1[c].w);
        bf16x8 a = __builtin_bit_cast(bf16x8, p);
        acc0 = __builtin_amdgcn_mfma_f32_16x16x32_bf16(a, b0[c], acc0, 0, 0, 0);
        acc1 = __builtin_amdgcn_mfma_f32_16x16x32_bf16(a, b1[c], acc1, 0, 0, 0);

        float4 w0 = *(const float4*)&wvec[dbase];
        float4 w1 = *(const float4*)&wvec[dbase + 4];
        f32x4  q0 = *(const f32x4*)&kk2s[dbase];
        f32x4  q1 = *(const f32x4*)&kk2s[dbase + 4];
        lin = fmaf(u0[c].x, w0.x, lin); lin = fmaf(u0[c].y, w0.y, lin);
        lin = fmaf(u0[c].z, w0.z, lin); lin = fmaf(u0[c].w, w0.w, lin);
        lin = fmaf(u1[c].x, w1.x, lin); lin = fmaf(u1[c].y, w1.y, lin);
        lin = fmaf(u1[c].z, w1.z, lin); lin = fmaf(u1[c].w, w1.w, lin);
        tq = fmaf(u0[c].x*u0[c].x, q0[0], tq); tq = fmaf(u0[c].y*u0[c].y, q0[1], tq);
        tq = fmaf(u0[c].z*u0[c].z, q0[2], tq); tq = fmaf(u0[c].w*u0[c].w, q0[3], tq);
        tq = fmaf(u1[c].x*u1[c].x, q1[0], tq); tq = fmaf(u1[c].y*u1[c].y, q1[1], tq);
        tq = fmaf(u1[c].z*u1[c].z, q1[2], tq); tq = fmaf(u1[c].w*u1[c].w, q1[3], tq);
    }

    // lin/t: reduce over the 4 kg slices (examples indexed by col)
    lin += __shfl_xor(lin, 16, 64);
    lin += __shfl_xor(lin, 32, 64);      // all lanes: full lin[example=col]
    tq  += __shfl_xor(tq, 16, 64);
    tq  += __shfl_xor(tq, 32, 64);       // all lanes: full t[example=col]

    // ---- 5. epilogue: C row = kg*4+r (example), col = k ----
    const float bval = bb[0];
    #pragma unroll
    for (int r = 0; r < 4; ++r) {
        float v = acc0[r]*acc0[r] + acc1[r]*acc1[r];   // s_k^2 pair
        #pragma unroll
        for (int m = 1; m <= 8; m <<= 1)
            v += __shfl_xor(v, m, 64);                 // sum over 16 k-cols
        float lm = __shfl(lin, kg * 4 + r, 64);
        float tm = __shfl(tq,  kg * 4 + r, 64);
        if (col == 0) {
            float z = lm + bval + 0.5f * (v - tm);
            out[tile * 16 + kg * 4 + r] = 1.0f / (1.0f + __expf(-z));
        }
    }
}

extern "C" void kernel_launch(void* const* d_in, const int* in_sizes, int n_in,
                              void* d_out, int out_size, void* d_ws, size_t ws_size,
                              hipStream_t stream) {
    const int*   inputs      = (const int*)  d_in[0];
    const float* user_table  = (const float*)d_in[1];
    const float* item_table  = (const float*)d_in[2];
    const float* feat_tables = (const float*)d_in[3];
    const float* w           = (const float*)d_in[4];
    const float* b           = (const float*)d_in[5];
    const float* k_mat       = (const float*)d_in[6];
    float* out = (float*)d_out;

    int nblocks = out_size / 64;    // 16384 / (4 waves * 16 examples) = 256
    fm_fused<<<nblocks, 256, 0, stream>>>(inputs, user_table, item_table,
                                          feat_tables, w, b, k_mat, out);
}